// Round 1
// baseline (847.806 us; speedup 1.0000x reference)
//
#include <hip/hip_runtime.h>
#include <math.h>

// Problem constants: B=128 queries, D=3*32*32=3072, N=50000 samples, 10 classes
#define D      3072
#define BK     64          // k per chunk
#define NCH    (D / BK)    // 48 chunks
#define BM     128         // samples per block (M of the MFMA GEMM)
#define NQ     128         // queries = all of them (N of the MFMA GEMM)
#define NCLS   10

typedef float   f32x4  __attribute__((ext_vector_type(4)));
typedef float   f32x16 __attribute__((ext_vector_type(16)));
typedef __bf16  bf16x8 __attribute__((ext_vector_type(8)));

// ---------------- workspace layout (bytes) ----------------
//  [0)                      gmin    : 128 * u64  (packed d2|idx argmin)
//  [1024)                   x2g     : 128 * f32  (exact ||x||^2)
//  [4096)                   xhi_swz : NCH * 16384 (bf16 hi query chunk images, swizzled)
//  [4096 + NCH*16384)       xlo_swz : NCH * 16384 (bf16 lo)
#define WS_GMIN 0
#define WS_X2   1024
#define WS_XHI  4096
#define WS_XLO  (4096 + NCH * 16384)

// ---------------------------------------------------------------------------
// Kernel 1 (prep): per-query ||x||^2, gmin init, and x -> bf16 hi/lo split
// written in the *swizzled LDS-image* layout so the dist kernel can stage it
// with linear global_load_lds and read fragments with the XOR bank-swizzle.
// ushort index within a chunk image: (q*64 + k) ^ ((q&7)<<3)
// grid = 128 blocks x 64 threads (one wave per query row)
// ---------------------------------------------------------------------------
__global__ __launch_bounds__(64) void prep_kernel(const float* __restrict__ x,
                                                  char* __restrict__ ws) {
    const int q = blockIdx.x;
    const int l = threadIdx.x;
    unsigned long long* gmin = (unsigned long long*)(ws + WS_GMIN);
    float* x2g = (float*)(ws + WS_X2);
    unsigned short* xhi = (unsigned short*)(ws + WS_XHI);
    unsigned short* xlo = (unsigned short*)(ws + WS_XLO);

    const float* xr = x + (size_t)q * D;
    const int swz = (q & 7) << 3;
    float v2 = 0.f;
    for (int c = 0; c < NCH; ++c) {
        float v = xr[c * 64 + l];
        v2 += v * v;
        __bf16 hb = (__bf16)v;
        float  hf = (float)hb;
        __bf16 lb = (__bf16)(v - hf);
        const int idx = c * 8192 + ((q * 64 + l) ^ swz);
        xhi[idx] = __builtin_bit_cast(unsigned short, hb);
        xlo[idx] = __builtin_bit_cast(unsigned short, lb);
    }
#pragma unroll
    for (int off = 32; off > 0; off >>= 1) v2 += __shfl_down(v2, off, 64);
    if (l == 0) { x2g[q] = v2; gmin[q] = ~0ull; }
}

// ---------------------------------------------------------------------------
// Kernel 2 (dist): split-bf16 MFMA GEMM  dot = hi*hi + hi*lo + lo*hi
// Block tile: 128 samples (A, M) x 128 queries (B, N), BK=64 per chunk.
// 4 waves, each owning a 64x64 quadrant as 2x2 mfma_f32_32x32x16_bf16 frags.
// A (samples) reg-staged fp32->hi/lo with exact fp32 s2 accumulated en route;
// B (queries) staged via global_load_lds from the pre-swizzled workspace.
// LDS XOR swizzle: byte L ^= (row&7)<<4 (applied on write AND read; for the
// B operand the workspace content is pre-swizzled so the DMA copy is linear).
// ---------------------------------------------------------------------------
__global__ __launch_bounds__(256, 2) void dist_kernel(const float* __restrict__ s,
                                                      char* __restrict__ ws,
                                                      int N) {
    // 64 KB LDS pool: tiles during the K loop; epilogue scratch aliases B tile.
    __shared__ __align__(16) char pool[65536];
    unsigned short* Ahi = (unsigned short*)(pool);            // 16 KB [128][64] swz
    unsigned short* Alo = (unsigned short*)(pool + 16384);    // 16 KB
    unsigned short* Bhi = (unsigned short*)(pool + 32768);    // 16 KB
    unsigned short* Blo = (unsigned short*)(pool + 49152);    // 16 KB
    // epilogue aliases (valid after final barrier of the K loop):
    float (*s2p)[16]            = (float (*)[16])(pool + 32768);        // 8 KB
    float* s2loc                = (float*)(pool + 32768 + 8192);        // 512 B
    unsigned long long (*qmin2)[NQ] =
        (unsigned long long (*)[NQ])(pool + 32768 + 8192 + 512);        // 2 KB

    const int tid   = threadIdx.x;
    const int nbase = blockIdx.x * BM;
    const float* x2g = (const float*)(ws + WS_X2);
    unsigned long long* gmin = (unsigned long long*)(ws + WS_GMIN);

    // ---- staging geometry: thread loads float4 (row = i*16 + (tid>>4), k-quad tid&15)
    const int c4 = tid & 15;
    const int r0 = tid >> 4;
    const float* gs[8];
    int   wofs[8];
    float s2a[8];
#pragma unroll
    for (int i = 0; i < 8; ++i) {
        const int r = i * 16 + r0;
        int g = nbase + r; if (g > N - 1) g = N - 1;     // clamp (excluded later)
        gs[i]   = s + (size_t)g * D + c4 * 4;
        wofs[i] = (r * 64 + c4 * 4) ^ ((r & 7) << 3);    // ushort units, 4-aligned
        s2a[i]  = 0.f;
    }

    // ---- wave/frag geometry
    const int lane = tid & 63;
    const int w    = tid >> 6;
    const int wr   = w >> 1;          // sample half (0/1)
    const int wc   = w & 1;           // query half (0/1)
    const int l31  = lane & 31;
    const int lhi  = lane >> 5;
    int aBase[2], aMask[2], bBase[2], bMask[2];
#pragma unroll
    for (int i = 0; i < 2; ++i) {
        const int row = wr * 64 + i * 32 + l31;   // sample row of A frag i
        aBase[i] = row * 64 + lhi * 8;            // ushort units
        aMask[i] = (row & 7) << 3;
        const int col = wc * 64 + i * 32 + l31;   // query col of B frag i
        bBase[i] = col * 64 + lhi * 8;
        bMask[i] = (col & 7) << 3;
    }

    f32x16 acc[2][2] = {};

    const char* xhiB = ws + WS_XHI;
    const char* xloB = ws + WS_XLO;

    for (int c = 0; c < NCH; ++c) {
        // -- async stage B (queries): linear 16 KB copies, content pre-swizzled
        {
            const char* gh = xhiB + (size_t)c * 16384 + tid * 16;
            const char* gl = xloB + (size_t)c * 16384 + tid * 16;
            char* lh = (char*)Bhi + tid * 16;
            char* ll = (char*)Blo + tid * 16;
#pragma unroll
            for (int u = 0; u < 4; ++u) {
                __builtin_amdgcn_global_load_lds(
                    (__attribute__((address_space(1))) void*)(gh + u * 4096),
                    (__attribute__((address_space(3))) void*)(lh + u * 4096), 16, 0, 0);
                __builtin_amdgcn_global_load_lds(
                    (__attribute__((address_space(1))) void*)(gl + u * 4096),
                    (__attribute__((address_space(3))) void*)(ll + u * 4096), 16, 0, 0);
            }
        }
        // -- stage A (samples): fp32 load, hi/lo convert, swizzled ds_write, s2
        f32x4 t[8];
#pragma unroll
        for (int i = 0; i < 8; ++i) t[i] = *(const f32x4*)(gs[i] + (size_t)c * 64);
#pragma unroll
        for (int i = 0; i < 8; ++i) {
            unsigned short h[4], lo[4];
#pragma unroll
            for (int e = 0; e < 4; ++e) {
                float v = t[i][e];
                __bf16 hb = (__bf16)v;
                float  hf = (float)hb;
                __bf16 lb = (__bf16)(v - hf);
                h[e]  = __builtin_bit_cast(unsigned short, hb);
                lo[e] = __builtin_bit_cast(unsigned short, lb);
                s2a[i] = fmaf(v, v, s2a[i]);
            }
            uint2 hp, lp;
            hp.x = (unsigned)h[0]  | ((unsigned)h[1]  << 16);
            hp.y = (unsigned)h[2]  | ((unsigned)h[3]  << 16);
            lp.x = (unsigned)lo[0] | ((unsigned)lo[1] << 16);
            lp.y = (unsigned)lo[2] | ((unsigned)lo[3] << 16);
            *(uint2*)&Ahi[wofs[i]] = hp;
            *(uint2*)&Alo[wofs[i]] = lp;
        }
        __syncthreads();   // staging (incl. DMA, compiler drains vmcnt) visible

        // -- compute: 4 k-steps x (2x2 frag pairs) x 3 products
#pragma unroll
        for (int ks = 0; ks < 4; ++ks) {
            bf16x8 a_h[2], a_l[2], b_h[2], b_l[2];
#pragma unroll
            for (int i = 0; i < 2; ++i) {
                a_h[i] = *(const bf16x8*)&Ahi[(aBase[i] + ks * 16) ^ aMask[i]];
                a_l[i] = *(const bf16x8*)&Alo[(aBase[i] + ks * 16) ^ aMask[i]];
                b_h[i] = *(const bf16x8*)&Bhi[(bBase[i] + ks * 16) ^ bMask[i]];
                b_l[i] = *(const bf16x8*)&Blo[(bBase[i] + ks * 16) ^ bMask[i]];
            }
#pragma unroll
            for (int i = 0; i < 2; ++i)
#pragma unroll
                for (int j = 0; j < 2; ++j) {
                    acc[i][j] = __builtin_amdgcn_mfma_f32_32x32x16_bf16(a_h[i], b_h[j], acc[i][j], 0, 0, 0);
                    acc[i][j] = __builtin_amdgcn_mfma_f32_32x32x16_bf16(a_h[i], b_l[j], acc[i][j], 0, 0, 0);
                    acc[i][j] = __builtin_amdgcn_mfma_f32_32x32x16_bf16(a_l[i], b_h[j], acc[i][j], 0, 0, 0);
                }
        }
        __syncthreads();   // compute done before next staging overwrites tiles
    }

    // ---- s2 reduce (epilogue scratch aliases B tile; all tile reads done) ----
#pragma unroll
    for (int i = 0; i < 8; ++i) s2p[i * 16 + r0][c4] = s2a[i];
    __syncthreads();
    if (tid < BM) {
        float t2 = 0.f;
#pragma unroll
        for (int j2 = 0; j2 < 16; ++j2) t2 += s2p[tid][j2];
        s2loc[tid] = t2;
    }
    __syncthreads();

    // ---- per-query packed argmin: C layout col=lane&31 (query),
    //      row=(reg&3)+8*(reg>>2)+4*(lane>>5) (sample within 32)
#pragma unroll
    for (int j = 0; j < 2; ++j) {
        const int q = wc * 64 + j * 32 + l31;
        const float x2q = x2g[q];
        unsigned long long m = ~0ull;
#pragma unroll
        for (int i = 0; i < 2; ++i) {
#pragma unroll
            for (int r = 0; r < 16; ++r) {
                const int rl = wr * 64 + i * 32 + (r & 3) + 8 * (r >> 2) + 4 * lhi;
                const int n  = nbase + rl;
                if (n < N) {
                    float d2 = fmaxf(x2q + s2loc[rl] - 2.f * acc[i][j][r], 0.f);
                    unsigned long long p =
                        ((unsigned long long)__float_as_uint(d2) << 32) | (unsigned)n;
                    m = p < m ? p : m;     // tie -> smaller n (numpy first-index)
                }
            }
        }
        unsigned long long o = __shfl_xor(m, 32, 64);
        m = o < m ? o : m;
        if (lane < 32) qmin2[wr][q] = m;
    }
    __syncthreads();
    if (tid < NQ) {
        unsigned long long m = qmin2[0][tid];
        unsigned long long o = qmin2[1][tid];
        m = o < m ? o : m;
        atomicMin(&gmin[tid], m);
    }
}

// ---------------------------------------------------------------------------
// Kernel 3 (out): unpack winner; EXACT fp32 recompute of d2 for l2s (so the
// bf16 approximation only ever influenced argmin selection); one-hot pred;
// fused imgs copy.  grid = B blocks x 256 threads
// ---------------------------------------------------------------------------
__global__ __launch_bounds__(256) void out_kernel(const float* __restrict__ x,
                                                  const float* __restrict__ s,
                                                  const int* __restrict__ classes,
                                                  const char* __restrict__ ws,
                                                  float* __restrict__ out, int B_) {
    const int b = blockIdx.x;
    const int tid = threadIdx.x;
    const unsigned long long* gmin = (const unsigned long long*)(ws + WS_GMIN);
    const unsigned idx = (unsigned)(gmin[b] & 0xffffffffu);

    float* pred = out;                                     // (B, NCLS)
    float* imgs = out + (size_t)B_ * NCLS;                 // (B, D)
    float* l2s  = out + (size_t)B_ * NCLS + (size_t)B_ * D;

    if (tid < NCLS) {
        const int cls = classes[idx];
        pred[b * NCLS + tid] = (tid == cls) ? 1.f : 0.f;
    }

    const f32x4* xs4 = (const f32x4*)(x + (size_t)b * D);
    const f32x4* sr4 = (const f32x4*)(s + (size_t)idx * D);
    f32x4* dst = (f32x4*)(imgs + (size_t)b * D);
    float part = 0.f;
    for (int t = tid; t < D / 4; t += 256) {
        f32x4 sv = sr4[t];
        f32x4 xv = xs4[t];
        dst[t] = sv;
        f32x4 d = xv - sv;
        part += d[0] * d[0] + d[1] * d[1] + d[2] * d[2] + d[3] * d[3];
    }
    __shared__ float wsum[4];
#pragma unroll
    for (int off = 32; off > 0; off >>= 1) part += __shfl_down(part, off, 64);
    if ((tid & 63) == 0) wsum[tid >> 6] = part;
    __syncthreads();
    if (tid == 0) l2s[b] = sqrtf(wsum[0] + wsum[1] + wsum[2] + wsum[3]);
}

// ---------------------------------------------------------------------------
extern "C" void kernel_launch(void* const* d_in, const int* in_sizes, int n_in,
                              void* d_out, int out_size, void* d_ws, size_t ws_size,
                              hipStream_t stream) {
    const float* x       = (const float*)d_in[0];   // (B, D) fp32
    const float* s       = (const float*)d_in[1];   // (N, D) fp32
    const int*   classes = (const int*)d_in[2];     // (N,) int32
    const int B_ = in_sizes[0] / D;                  // 128
    const int N  = in_sizes[2];                      // 50000
    char* ws = (char*)d_ws;                          // needs ~1.6 MB

    prep_kernel<<<B_, 64, 0, stream>>>(x, ws);

    const int nblocks = (N + BM - 1) / BM;           // 391
    dist_kernel<<<nblocks, 256, 0, stream>>>(s, ws, N);

    out_kernel<<<B_, 256, 0, stream>>>(x, s, classes, ws, (float*)d_out, B_);
}

// Round 2
// 833.863 us; speedup vs baseline: 1.0167x; 1.0167x over previous
//
#include <hip/hip_runtime.h>
#include <math.h>

// Problem constants: B=128 queries, D=3*32*32=3072, N=50000 samples, 10 classes
#define D      3072
#define BK     64          // k per chunk
#define NCH    (D / BK)    // 48 chunks
#define BM     128         // samples per block (M of the MFMA GEMM)
#define NQ     128         // queries = all of them (N of the MFMA GEMM)
#define NCLS   10

typedef float   f32x4  __attribute__((ext_vector_type(4)));
typedef float   f32x16 __attribute__((ext_vector_type(16)));
typedef __bf16  bf16x8 __attribute__((ext_vector_type(8)));

// ---------------- workspace layout (bytes) ----------------
#define WS_GMIN 0
#define WS_X2   1024
#define WS_XHI  4096
#define WS_XLO  (4096 + NCH * 16384)

// ---------------------------------------------------------------------------
// Kernel 1 (prep): per-query ||x||^2, gmin init, x -> bf16 hi/lo split into
// the pre-swizzled chunk-image layout (ushort idx within chunk image:
// (q*64 + k) ^ ((q&7)<<3)).  256 threads/block, float4 loads: each thread
// handles 3 k-quads; 4-aligned quads are XOR-invariant in bits 0..1 so each
// quad packs to one uint2 store per tile.
// ---------------------------------------------------------------------------
__global__ __launch_bounds__(256) void prep_kernel(const float* __restrict__ x,
                                                   char* __restrict__ ws) {
    const int q   = blockIdx.x;
    const int tid = threadIdx.x;
    unsigned long long* gmin = (unsigned long long*)(ws + WS_GMIN);
    float* x2g = (float*)(ws + WS_X2);
    unsigned short* xhi = (unsigned short*)(ws + WS_XHI);
    unsigned short* xlo = (unsigned short*)(ws + WS_XLO);

    const float* xr = x + (size_t)q * D;
    const int swz = (q & 7) << 3;
    float v2 = 0.f;
#pragma unroll
    for (int i = 0; i < 3; ++i) {
        const int f  = tid + i * 256;        // flat quad index 0..767
        const int c  = f >> 4;               // chunk (64 k = 16 quads)
        const int l4 = (f & 15) * 4;         // k within chunk, 4-aligned
        f32x4 v = *(const f32x4*)(xr + f * 4);
        unsigned short h[4], lo[4];
#pragma unroll
        for (int e = 0; e < 4; ++e) {
            float val = v[e];
            v2 = fmaf(val, val, v2);
            __bf16 hb = (__bf16)val;
            float  hf = (float)hb;
            __bf16 lb = (__bf16)(val - hf);
            h[e]  = __builtin_bit_cast(unsigned short, hb);
            lo[e] = __builtin_bit_cast(unsigned short, lb);
        }
        const int idx = c * 8192 + ((q * 64 + l4) ^ swz);
        uint2 hp, lp;
        hp.x = (unsigned)h[0]  | ((unsigned)h[1]  << 16);
        hp.y = (unsigned)h[2]  | ((unsigned)h[3]  << 16);
        lp.x = (unsigned)lo[0] | ((unsigned)lo[1] << 16);
        lp.y = (unsigned)lo[2] | ((unsigned)lo[3] << 16);
        *(uint2*)&xhi[idx] = hp;
        *(uint2*)&xlo[idx] = lp;
    }
#pragma unroll
    for (int off = 32; off > 0; off >>= 1) v2 += __shfl_down(v2, off, 64);
    __shared__ float wsum[4];
    if ((tid & 63) == 0) wsum[tid >> 6] = v2;
    __syncthreads();
    if (tid == 0) {
        x2g[q] = wsum[0] + wsum[1] + wsum[2] + wsum[3];
        gmin[q] = ~0ull;
    }
}

// ---------------------------------------------------------------------------
// Kernel 2 (dist): split-bf16 MFMA GEMM, pipelined chunk loop.
// Steady-state per chunk (order pinned by sched_barrier(0) fences so the
// manual vmcnt count is valid):
//   [s_barrier]  issue B-DMA(c) x8 (oldest)  |  convert prefetched A(c) regs
//   -> swizzled ds_write  |  issue A(c+1) global loads x8 (newest)
//   -> s_waitcnt vmcnt(8) lgkmcnt(0)   (B-DMA drained, A(c+1) IN FLIGHT)
//   -> s_barrier -> ds_read frags + 12 MFMA x4 ks -> s_barrier
// A(c+1) loads complete under the MFMA phase instead of stalling the barrier.
// ---------------------------------------------------------------------------
__global__ __launch_bounds__(256, 2) void dist_kernel(const float* __restrict__ s,
                                                      char* __restrict__ ws,
                                                      int N) {
    __shared__ __align__(16) char pool[65536];
    unsigned short* Ahi = (unsigned short*)(pool);            // 16 KB [128][64] swz
    unsigned short* Alo = (unsigned short*)(pool + 16384);    // 16 KB
    unsigned short* Bhi = (unsigned short*)(pool + 32768);    // 16 KB
    unsigned short* Blo = (unsigned short*)(pool + 49152);    // 16 KB
    float (*s2p)[16]            = (float (*)[16])(pool + 32768);        // epilogue alias
    float* s2loc                = (float*)(pool + 32768 + 8192);
    unsigned long long (*qmin2)[NQ] =
        (unsigned long long (*)[NQ])(pool + 32768 + 8192 + 512);

    const int tid   = threadIdx.x;
    const int nbase = blockIdx.x * BM;
    const float* x2g = (const float*)(ws + WS_X2);
    unsigned long long* gmin = (unsigned long long*)(ws + WS_GMIN);

    // staging geometry: thread loads float4 (row = i*16 + tid>>4, k-quad tid&15)
    const int c4 = tid & 15;
    const int r0 = tid >> 4;
    const float* gs[8];
    int   wofs[8];
    float s2a[8];
#pragma unroll
    for (int i = 0; i < 8; ++i) {
        const int r = i * 16 + r0;
        int g = nbase + r; if (g > N - 1) g = N - 1;     // clamp (excluded later)
        gs[i]   = s + (size_t)g * D + c4 * 4;
        wofs[i] = (r * 64 + c4 * 4) ^ ((r & 7) << 3);    // ushort units, 4-aligned
        s2a[i]  = 0.f;
    }

    // wave/frag geometry
    const int lane = tid & 63;
    const int w    = tid >> 6;
    const int wr   = w >> 1;
    const int wc   = w & 1;
    const int l31  = lane & 31;
    const int lhi  = lane >> 5;
    int aBase[2], aMask[2], bBase[2], bMask[2];
#pragma unroll
    for (int i = 0; i < 2; ++i) {
        const int row = wr * 64 + i * 32 + l31;
        aBase[i] = row * 64 + lhi * 8;
        aMask[i] = (row & 7) << 3;
        const int col = wc * 64 + i * 32 + l31;
        bBase[i] = col * 64 + lhi * 8;
        bMask[i] = (col & 7) << 3;
    }

    f32x16 acc[2][2] = {};

    const char* xhiB = ws + WS_XHI;
    const char* xloB = ws + WS_XLO;

    // prologue: prefetch A chunk 0 into registers
    f32x4 t[8];
#pragma unroll
    for (int i = 0; i < 8; ++i) t[i] = *(const f32x4*)(gs[i]);

    for (int c = 0; c < NCH; ++c) {
        // -- phase 1: issue B-DMA(c) (oldest outstanding group)
        {
            const char* gh = xhiB + (size_t)c * 16384 + tid * 16;
            const char* gl = xloB + (size_t)c * 16384 + tid * 16;
            char* lh = (char*)Bhi + tid * 16;
            char* ll = (char*)Blo + tid * 16;
#pragma unroll
            for (int u = 0; u < 4; ++u) {
                __builtin_amdgcn_global_load_lds(
                    (__attribute__((address_space(1))) void*)(gh + u * 4096),
                    (__attribute__((address_space(3))) void*)(lh + u * 4096), 16, 0, 0);
                __builtin_amdgcn_global_load_lds(
                    (__attribute__((address_space(1))) void*)(gl + u * 4096),
                    (__attribute__((address_space(3))) void*)(ll + u * 4096), 16, 0, 0);
            }
        }
        __builtin_amdgcn_sched_barrier(0);   // pin: DMA stays oldest

        // -- phase 2: convert prefetched A(c) regs -> swizzled ds_write (+s2)
#pragma unroll
        for (int i = 0; i < 8; ++i) {
            unsigned short h[4], lo[4];
#pragma unroll
            for (int e = 0; e < 4; ++e) {
                float v = t[i][e];
                __bf16 hb = (__bf16)v;
                float  hf = (float)hb;
                __bf16 lb = (__bf16)(v - hf);
                h[e]  = __builtin_bit_cast(unsigned short, hb);
                lo[e] = __builtin_bit_cast(unsigned short, lb);
                s2a[i] = fmaf(v, v, s2a[i]);
            }
            uint2 hp, lp;
            hp.x = (unsigned)h[0]  | ((unsigned)h[1]  << 16);
            hp.y = (unsigned)h[2]  | ((unsigned)h[3]  << 16);
            lp.x = (unsigned)lo[0] | ((unsigned)lo[1] << 16);
            lp.y = (unsigned)lo[2] | ((unsigned)lo[3] << 16);
            *(uint2*)&Ahi[wofs[i]] = hp;
            *(uint2*)&Alo[wofs[i]] = lp;
        }
        __builtin_amdgcn_sched_barrier(0);

        // -- phase 3: prefetch A(c+1) into regs (newest outstanding group)
        if (c + 1 < NCH) {
#pragma unroll
            for (int i = 0; i < 8; ++i)
                t[i] = *(const f32x4*)(gs[i] + (size_t)(c + 1) * 64);
        }
        __builtin_amdgcn_sched_barrier(0);

        // -- phase 4: wait B-DMA (counted: 8 prefetch loads stay in flight)
        if (c + 1 < NCH) {
            asm volatile("s_waitcnt vmcnt(8) lgkmcnt(0)" ::: "memory");
        } else {
            asm volatile("s_waitcnt vmcnt(0) lgkmcnt(0)" ::: "memory");
        }
        __builtin_amdgcn_sched_barrier(0);
        __builtin_amdgcn_s_barrier();
        __builtin_amdgcn_sched_barrier(0);

        // -- phase 5: compute (A(c+1) loads complete under the MFMAs)
#pragma unroll
        for (int ks = 0; ks < 4; ++ks) {
            bf16x8 a_h[2], a_l[2], b_h[2], b_l[2];
#pragma unroll
            for (int i = 0; i < 2; ++i) {
                a_h[i] = *(const bf16x8*)&Ahi[(aBase[i] + ks * 16) ^ aMask[i]];
                a_l[i] = *(const bf16x8*)&Alo[(aBase[i] + ks * 16) ^ aMask[i]];
                b_h[i] = *(const bf16x8*)&Bhi[(bBase[i] + ks * 16) ^ bMask[i]];
                b_l[i] = *(const bf16x8*)&Blo[(bBase[i] + ks * 16) ^ bMask[i]];
            }
#pragma unroll
            for (int i = 0; i < 2; ++i)
#pragma unroll
                for (int j = 0; j < 2; ++j) {
                    acc[i][j] = __builtin_amdgcn_mfma_f32_32x32x16_bf16(a_h[i], b_h[j], acc[i][j], 0, 0, 0);
                    acc[i][j] = __builtin_amdgcn_mfma_f32_32x32x16_bf16(a_h[i], b_l[j], acc[i][j], 0, 0, 0);
                    acc[i][j] = __builtin_amdgcn_mfma_f32_32x32x16_bf16(a_l[i], b_h[j], acc[i][j], 0, 0, 0);
                }
        }
        __builtin_amdgcn_s_barrier();        // tiles free for next chunk
        __builtin_amdgcn_sched_barrier(0);
    }

    // ---- s2 reduce (epilogue scratch aliases B tile) ----
#pragma unroll
    for (int i = 0; i < 8; ++i) s2p[i * 16 + r0][c4] = s2a[i];
    __syncthreads();
    if (tid < BM) {
        float t2 = 0.f;
#pragma unroll
        for (int j2 = 0; j2 < 16; ++j2) t2 += s2p[tid][j2];
        s2loc[tid] = t2;
    }
    __syncthreads();

    // ---- per-query packed argmin: C layout col=lane&31 (query),
    //      row=(reg&3)+8*(reg>>2)+4*(lane>>5) (sample within 32)
#pragma unroll
    for (int j = 0; j < 2; ++j) {
        const int q = wc * 64 + j * 32 + l31;
        const float x2q = x2g[q];
        unsigned long long m = ~0ull;
#pragma unroll
        for (int i = 0; i < 2; ++i) {
#pragma unroll
            for (int r = 0; r < 16; ++r) {
                const int rl = wr * 64 + i * 32 + (r & 3) + 8 * (r >> 2) + 4 * lhi;
                const int n  = nbase + rl;
                if (n < N) {
                    float d2 = fmaxf(x2q + s2loc[rl] - 2.f * acc[i][j][r], 0.f);
                    unsigned long long p =
                        ((unsigned long long)__float_as_uint(d2) << 32) | (unsigned)n;
                    m = p < m ? p : m;     // tie -> smaller n (numpy first-index)
                }
            }
        }
        unsigned long long o = __shfl_xor(m, 32, 64);
        m = o < m ? o : m;
        if (lane < 32) qmin2[wr][q] = m;
    }
    __syncthreads();
    if (tid < NQ) {
        unsigned long long m = qmin2[0][tid];
        unsigned long long o = qmin2[1][tid];
        m = o < m ? o : m;
        atomicMin(&gmin[tid], m);
    }
}

// ---------------------------------------------------------------------------
// Kernel 3 (out): unpack winner; EXACT fp32 recompute of d2 for l2s; one-hot
// pred; fused imgs copy.
// ---------------------------------------------------------------------------
__global__ __launch_bounds__(256) void out_kernel(const float* __restrict__ x,
                                                  const float* __restrict__ s,
                                                  const int* __restrict__ classes,
                                                  const char* __restrict__ ws,
                                                  float* __restrict__ out, int B_) {
    const int b = blockIdx.x;
    const int tid = threadIdx.x;
    const unsigned long long* gmin = (const unsigned long long*)(ws + WS_GMIN);
    const unsigned idx = (unsigned)(gmin[b] & 0xffffffffu);

    float* pred = out;                                     // (B, NCLS)
    float* imgs = out + (size_t)B_ * NCLS;                 // (B, D)
    float* l2s  = out + (size_t)B_ * NCLS + (size_t)B_ * D;

    if (tid < NCLS) {
        const int cls = classes[idx];
        pred[b * NCLS + tid] = (tid == cls) ? 1.f : 0.f;
    }

    const f32x4* xs4 = (const f32x4*)(x + (size_t)b * D);
    const f32x4* sr4 = (const f32x4*)(s + (size_t)idx * D);
    f32x4* dst = (f32x4*)(imgs + (size_t)b * D);
    float part = 0.f;
    for (int t = tid; t < D / 4; t += 256) {
        f32x4 sv = sr4[t];
        f32x4 xv = xs4[t];
        dst[t] = sv;
        f32x4 d = xv - sv;
        part += d[0] * d[0] + d[1] * d[1] + d[2] * d[2] + d[3] * d[3];
    }
    __shared__ float wsum[4];
#pragma unroll
    for (int off = 32; off > 0; off >>= 1) part += __shfl_down(part, off, 64);
    if ((tid & 63) == 0) wsum[tid >> 6] = part;
    __syncthreads();
    if (tid == 0) l2s[b] = sqrtf(wsum[0] + wsum[1] + wsum[2] + wsum[3]);
}

// ---------------------------------------------------------------------------
extern "C" void kernel_launch(void* const* d_in, const int* in_sizes, int n_in,
                              void* d_out, int out_size, void* d_ws, size_t ws_size,
                              hipStream_t stream) {
    const float* x       = (const float*)d_in[0];   // (B, D) fp32
    const float* s       = (const float*)d_in[1];   // (N, D) fp32
    const int*   classes = (const int*)d_in[2];     // (N,) int32
    const int B_ = in_sizes[0] / D;                  // 128
    const int N  = in_sizes[2];                      // 50000
    char* ws = (char*)d_ws;                          // ~1.6 MB used

    prep_kernel<<<B_, 256, 0, stream>>>(x, ws);

    const int nblocks = (N + BM - 1) / BM;           // 391
    dist_kernel<<<nblocks, 256, 0, stream>>>(s, ws, N);

    out_kernel<<<B_, 256, 0, stream>>>(x, s, classes, ws, (float*)d_out, B_);
}